// Round 4
// baseline (87.987 us; speedup 1.0000x reference)
//
#include <hip/hip_runtime.h>
#include <stdint.h>

constexpr int L_LEVELS = 16;
constexpr int T_SIZE   = 16384;
constexpr int N_PTS    = 262144;

typedef _Float16 h2 __attribute__((ext_vector_type(2)));
typedef _Float16 h8 __attribute__((ext_vector_type(8)));

// Byte-offset-scaled hash constants: prime*4 mod 2^32, mask (T-1)*4.
constexpr uint32_t P1_4 = 2654435761u * 4u;
constexpr uint32_t P2_4 = 805459861u * 4u;
constexpr uint32_t M4   = (T_SIZE - 1) * 4u;   // 65532

__device__ __forceinline__ h2 lerp2(h2 a, h2 b, h2 t) {
    return a + t * (b - a);                     // v_pk_sub + v_pk_fma
}

// ---------------------------------------------------------------------------
// Kernel A: block = (level, chunk of 4096 points), 512 threads.
// Level table in LDS as half2 (64 KB -> 2 blocks/CU, 16 waves/CU).
// Gray-code XOR addressing for the 8 corner gathers; packed-fp16 lerp tree.
// ---------------------------------------------------------------------------
template <bool DIRECT>
__global__ __launch_bounds__(512, 4) void hash_encode_lds(
    const float* __restrict__ x,
    const float* __restrict__ emb,
    void* __restrict__ dst_raw)
{
    __shared__ h2 tab[T_SIZE];                  // 64 KB

    const int l     = blockIdx.x & (L_LEVELS - 1);
    const int chunk = blockIdx.x >> 4;          // 0..63
    const int t     = threadIdx.x;              // 0..511
    const int base  = chunk * 4096;

    // ---- stage table: 16384 half2 entries, 16 B (4 entries) per thread/iter
    {
        const float4* __restrict__ src =
            reinterpret_cast<const float4*>(emb + (size_t)l * T_SIZE * 2);
        h8* __restrict__ d8 = reinterpret_cast<h8*>(tab);
#pragma unroll
        for (int it = 0; it < 8; ++it) {
            const int i = it * 512 + t;         // < 4096
            float4 a = src[2 * i];
            float4 b = src[2 * i + 1];
            h8 w = { (_Float16)a.x, (_Float16)a.y, (_Float16)a.z, (_Float16)a.w,
                     (_Float16)b.x, (_Float16)b.y, (_Float16)b.z, (_Float16)b.w };
            d8[i] = w;                          // ds_write_b128, conflict-free
        }
    }
    __syncthreads();

    // N_l = 16 * 2^(5l/16); l*0.3125f exact.
    const float Nl = 16.0f * exp2f((float)l * 0.3125f);
    const char* __restrict__ tb = reinterpret_cast<const char*>(tab);

#pragma unroll 2
    for (int p = 0; p < 8; ++p) {
        const int n = base + p * 512 + t;

        const float u0 = x[n * 3 + 0] * Nl;
        const float u1 = x[n * 3 + 1] * Nl;
        const float u2 = x[n * 3 + 2] * Nl;

        // x >= 0 so u >= 0; df = u - floor(u) matches the reference in both
        // the generic (d=1) and exact-integer (d=0 -> diff=0) cases.
        const float fl0 = floorf(u0), fl1 = floorf(u1), fl2 = floorf(u2);
        const float df0 = u0 - fl0, df1 = u1 - fl1, df2 = u2 - fl2;

        // Byte-offset hash products for the lo corner (prime*4, wrapping).
        const uint32_t q0 = ((uint32_t)(int32_t)fl0) << 2;       // prime 1
        const uint32_t q1 = ((uint32_t)(int32_t)fl1) * P1_4;
        const uint32_t q2 = ((uint32_t)(int32_t)fl2) * P2_4;
        // hi = lo + 1: if u integral this gathers a "wrong" slot, but t=0
        // makes that lerp contribution exactly 0 -> still correct.
        // Masked XOR deltas per dim ((a^b)&M4, XOR/AND/<<2 all distribute).
        const uint32_t d0 = (q0 ^ (q0 + 4u))   & M4;
        const uint32_t d1 = (q1 ^ (q1 + P1_4)) & M4;
        const uint32_t d2 = (q2 ^ (q2 + P2_4)) & M4;

        uint32_t off = (q0 ^ q1 ^ q2) & M4;     // corner 000 byte offset

        // Gray-code gather order: one XOR per subsequent corner address.
        constexpr int gray[8] = {0, 1, 3, 2, 6, 7, 5, 4};
        h2 f[8];
#pragma unroll
        for (int j = 0; j < 8; ++j) {
            f[gray[j]] = *reinterpret_cast<const h2*>(tb + off);  // ds_read_b32
            if (j < 7) {
                const int tog = gray[j] ^ gray[j + 1];            // 1,2 or 4
                off ^= (tog == 4) ? d0 : (tog == 2) ? d1 : d2;
            }
        }

        // Packed-fp16 trilinear lerp tree (both features per register).
        const _Float16 h0 = (_Float16)df0, h1 = (_Float16)df1, h2v = (_Float16)df2;
        const h2 t0 = {h0, h0}, t1 = {h1, h1}, t2 = {h2v, h2v};
        h2 e0 = lerp2(f[0], f[1], t2);
        h2 e1 = lerp2(f[2], f[3], t2);
        h2 e2 = lerp2(f[4], f[5], t2);
        h2 e3 = lerp2(f[6], f[7], t2);
        h2 g0 = lerp2(e0, e1, t1);
        h2 g1 = lerp2(e2, e3, t1);
        h2 r  = lerp2(g0, g1, t0);

        if (DIRECT) {
            float2* out = reinterpret_cast<float2*>(dst_raw);
            out[(size_t)n * L_LEVELS + l] = make_float2((float)r.x, (float)r.y);
        } else {
            reinterpret_cast<h2*>(dst_raw)[(size_t)l * N_PTS + n] = r;  // coalesced
        }
    }
}

// ---------------------------------------------------------------------------
// Kernel B: transpose ws (L, N) half2 -> out (N, L) float2 via LDS tile.
// ---------------------------------------------------------------------------
__global__ __launch_bounds__(256) void transpose_lnf_nlf(
    const h2* __restrict__ ws,
    float2* __restrict__ out)
{
    __shared__ h2 tile[L_LEVELS][257];
    const int t    = threadIdx.x;
    const int base = blockIdx.x * 256;

#pragma unroll
    for (int l = 0; l < L_LEVELS; ++l)
        tile[l][t] = ws[(size_t)l * N_PTS + base + t];   // coalesced 4 B/lane
    __syncthreads();

#pragma unroll
    for (int i = 0; i < L_LEVELS; ++i) {
        const int flat = i * 256 + t;                    // p*16 + l
        const int p = flat >> 4;
        const int l = flat & 15;
        h2 v = tile[l][p];
        out[(size_t)base * L_LEVELS + flat] =
            make_float2((float)v.x, (float)v.y);         // coalesced 8 B/lane
    }
}

extern "C" void kernel_launch(void* const* d_in, const int* in_sizes, int n_in,
                              void* d_out, int out_size, void* d_ws, size_t ws_size,
                              hipStream_t stream) {
    const float* x   = (const float*)d_in[0];
    const float* emb = (const float*)d_in[1];

    const size_t ws_needed = (size_t)N_PTS * L_LEVELS * sizeof(h2); // 16 MiB

    if (ws_size >= ws_needed) {
        hash_encode_lds<false><<<1024, 512, 0, stream>>>(x, emb, d_ws);
        transpose_lnf_nlf<<<N_PTS / 256, 256, 0, stream>>>((const h2*)d_ws,
                                                           (float2*)d_out);
    } else {
        hash_encode_lds<true><<<1024, 512, 0, stream>>>(x, emb, d_out);
    }
}

// Round 5
// 86.452 us; speedup vs baseline: 1.0178x; 1.0178x over previous
//
#include <hip/hip_runtime.h>
#include <stdint.h>

constexpr int L_LEVELS = 16;
constexpr int T_SIZE   = 16384;
constexpr int N_PTS    = 262144;

typedef _Float16 h2 __attribute__((ext_vector_type(2)));
typedef _Float16 h8 __attribute__((ext_vector_type(8)));

// Byte-offset-scaled hash constants: prime*4 mod 2^32, mask (T-1)*4.
constexpr uint32_t P1_4 = 2654435761u * 4u;
constexpr uint32_t P2_4 = 805459861u * 4u;
constexpr uint32_t M4   = (T_SIZE - 1) * 4u;   // 65532

__device__ __forceinline__ h2 lerp2(h2 a, h2 b, h2 t) {
    return a + t * (b - a);                     // v_pk_sub + v_pk_fma
}

// ---------------------------------------------------------------------------
// Kernel A: block = (level, chunk of 4096 points), 512 threads.
// Each thread owns 8 CONSECUTIVE points: x arrives as 6 float4 loads (96 B
// contiguous), results leave as 2 dwordx4 stores. Level table in LDS as
// half2 (64 KB -> 2 blocks/CU). Gray-code XOR corner addressing, packed
// fp16 lerp tree.
// ---------------------------------------------------------------------------
template <bool DIRECT>
__global__ __launch_bounds__(512, 4) void hash_encode_lds(
    const float* __restrict__ x,
    const float* __restrict__ emb,
    void* __restrict__ dst_raw)
{
    __shared__ h2 tab[T_SIZE];                  // 64 KB

    const int l     = blockIdx.x & (L_LEVELS - 1);
    const int chunk = blockIdx.x >> 4;          // 0..63
    const int t     = threadIdx.x;              // 0..511
    const int n0    = chunk * 4096 + t * 8;     // first of 8 consecutive points

    // ---- stage table: 16384 half2 entries, 16 B (4 entries) per thread/iter
    {
        const float4* __restrict__ src =
            reinterpret_cast<const float4*>(emb + (size_t)l * T_SIZE * 2);
        h8* __restrict__ d8 = reinterpret_cast<h8*>(tab);
#pragma unroll
        for (int it = 0; it < 8; ++it) {
            const int i = it * 512 + t;         // < 4096
            float4 a = src[2 * i];
            float4 b = src[2 * i + 1];
            h8 w = { (_Float16)a.x, (_Float16)a.y, (_Float16)a.z, (_Float16)a.w,
                     (_Float16)b.x, (_Float16)b.y, (_Float16)b.z, (_Float16)b.w };
            d8[i] = w;                          // ds_write_b128, conflict-free
        }
    }

    // ---- prefetch this thread's 8 points (24 floats = 6 float4, aligned) ---
    union { float4 q[6]; float f[24]; } xs;
    {
        const float4* __restrict__ xv =
            reinterpret_cast<const float4*>(x + (size_t)n0 * 3);
#pragma unroll
        for (int i = 0; i < 6; ++i) xs.q[i] = xv[i];
    }

    __syncthreads();

    // N_l = 16 * 2^(5l/16); l*0.3125f exact.
    const float Nl = 16.0f * exp2f((float)l * 0.3125f);
    const char* __restrict__ tb = reinterpret_cast<const char*>(tab);

    union { h2 r[8]; float4 q[2]; } res;

#pragma unroll
    for (int p = 0; p < 8; ++p) {
        const float u0 = xs.f[3 * p + 0] * Nl;
        const float u1 = xs.f[3 * p + 1] * Nl;
        const float u2 = xs.f[3 * p + 2] * Nl;

        // u >= 0: df = u - floor(u); exact-integer case gives df=0 which
        // zeroes the (possibly wrong-slot) hi-corner lerp term -> correct.
        const float fl0 = floorf(u0), fl1 = floorf(u1), fl2 = floorf(u2);
        const float df0 = u0 - fl0, df1 = u1 - fl1, df2 = u2 - fl2;

        // Byte-offset hash products for the lo corner (prime*4, wrapping).
        const uint32_t q0 = ((uint32_t)(int32_t)fl0) << 2;       // prime 1
        const uint32_t q1 = ((uint32_t)(int32_t)fl1) * P1_4;
        const uint32_t q2 = ((uint32_t)(int32_t)fl2) * P2_4;
        // Masked XOR deltas per dim ((a^b)&M4; <<2 / mul distribute mod 2^32)
        const uint32_t d0 = (q0 ^ (q0 + 4u))   & M4;
        const uint32_t d1 = (q1 ^ (q1 + P1_4)) & M4;
        const uint32_t d2 = (q2 ^ (q2 + P2_4)) & M4;

        uint32_t off = (q0 ^ q1 ^ q2) & M4;     // corner 000 byte offset

        // Gray-code gather order: one XOR per subsequent corner address.
        constexpr int gray[8] = {0, 1, 3, 2, 6, 7, 5, 4};
        h2 f[8];
#pragma unroll
        for (int j = 0; j < 8; ++j) {
            f[gray[j]] = *reinterpret_cast<const h2*>(tb + off);  // ds_read_b32
            if (j < 7) {
                const int tog = gray[j] ^ gray[j + 1];            // 1,2 or 4
                off ^= (tog == 4) ? d0 : (tog == 2) ? d1 : d2;
            }
        }

        // Packed-fp16 trilinear lerp tree (both features per register).
        const _Float16 h0 = (_Float16)df0, h1 = (_Float16)df1, hv2 = (_Float16)df2;
        const h2 t0 = {h0, h0}, t1 = {h1, h1}, t2 = {hv2, hv2};
        h2 e0 = lerp2(f[0], f[1], t2);
        h2 e1 = lerp2(f[2], f[3], t2);
        h2 e2 = lerp2(f[4], f[5], t2);
        h2 e3 = lerp2(f[6], f[7], t2);
        h2 g0 = lerp2(e0, e1, t1);
        h2 g1 = lerp2(e2, e3, t1);
        res.r[p] = lerp2(g0, g1, t0);
    }

    if (DIRECT) {
        float2* out = reinterpret_cast<float2*>(dst_raw);
#pragma unroll
        for (int p = 0; p < 8; ++p)
            out[(size_t)(n0 + p) * L_LEVELS + l] =
                make_float2((float)res.r[p].x, (float)res.r[p].y);
    } else {
        // ws[l*N + n0 .. n0+7] as half2: 32 B contiguous -> 2 dwordx4 stores.
        float4* ws4 = reinterpret_cast<float4*>(
            reinterpret_cast<h2*>(dst_raw) + (size_t)l * N_PTS + n0);
        ws4[0] = res.q[0];
        ws4[1] = res.q[1];
    }
}

// ---------------------------------------------------------------------------
// Kernel B: transpose ws (L, N) half2 -> out (N, L) float2 via LDS tile.
// ---------------------------------------------------------------------------
__global__ __launch_bounds__(256) void transpose_lnf_nlf(
    const h2* __restrict__ ws,
    float2* __restrict__ out)
{
    __shared__ h2 tile[L_LEVELS][257];
    const int t    = threadIdx.x;
    const int base = blockIdx.x * 256;

#pragma unroll
    for (int l = 0; l < L_LEVELS; ++l)
        tile[l][t] = ws[(size_t)l * N_PTS + base + t];   // coalesced 4 B/lane
    __syncthreads();

#pragma unroll
    for (int i = 0; i < L_LEVELS; ++i) {
        const int flat = i * 256 + t;                    // p*16 + l
        const int p = flat >> 4;
        const int l = flat & 15;
        h2 v = tile[l][p];
        out[(size_t)base * L_LEVELS + flat] =
            make_float2((float)v.x, (float)v.y);         // coalesced 8 B/lane
    }
}

extern "C" void kernel_launch(void* const* d_in, const int* in_sizes, int n_in,
                              void* d_out, int out_size, void* d_ws, size_t ws_size,
                              hipStream_t stream) {
    const float* x   = (const float*)d_in[0];
    const float* emb = (const float*)d_in[1];

    const size_t ws_needed = (size_t)N_PTS * L_LEVELS * sizeof(h2); // 16 MiB

    if (ws_size >= ws_needed) {
        hash_encode_lds<false><<<1024, 512, 0, stream>>>(x, emb, d_ws);
        transpose_lnf_nlf<<<N_PTS / 256, 256, 0, stream>>>((const h2*)d_ws,
                                                           (float2*)d_out);
    } else {
        hash_encode_lds<true><<<1024, 512, 0, stream>>>(x, emb, d_out);
    }
}